// Round 1
// baseline (1794.972 us; speedup 1.0000x reference)
//
#include <hip/hip_runtime.h>

#define D_DIM 2560
#define T_DIM 4096
#define B_DIM 4
#define H_DIM 10
#define DH 256
#define TW_DIM 4
#define M_DIM (B_DIM * T_DIM)   // 16384
#define CHUNKS 64
#define TC (T_DIM / CHUNKS)     // 64

typedef _Float16 f16;
typedef __attribute__((ext_vector_type(8))) _Float16 f16x8;
typedef __attribute__((ext_vector_type(4))) _Float16 f16x4;
typedef __attribute__((ext_vector_type(4))) float f32x4;

// ---------------- convert f32 -> f16 (vectorized x4) ----------------
__global__ void cvt_f16_kernel(const float* __restrict__ in, f16* __restrict__ out, long n4) {
  long i = (long)blockIdx.x * blockDim.x + threadIdx.x;
  if (i >= n4) return;
  f32x4 v = ((const f32x4*)in)[i];
  f16x4 o;
  o[0] = (f16)v[0]; o[1] = (f16)v[1]; o[2] = (f16)v[2]; o[3] = (f16)v[3];
  ((f16x4*)out)[i] = o;
}

// ---------------- transpose + convert: in [R,C] f32 -> out [C,R] f16, batched by z ----------------
__global__ void transpose_cvt_kernel(const float* __restrict__ in, f16* __restrict__ out, int R, int C) {
  __shared__ float tile[32][33];
  long zoff = (long)blockIdx.z * R * C;
  int c0 = blockIdx.x * 32, r0 = blockIdx.y * 32;
  int tx = threadIdx.x, ty = threadIdx.y;
  for (int i = ty; i < 32; i += 8)
    tile[i][tx] = in[zoff + (long)(r0 + i) * C + (c0 + tx)];
  __syncthreads();
  for (int i = ty; i < 32; i += 8)
    out[zoff + (long)(c0 + i) * R + (r0 + tx)] = (f16)tile[tx][i];
}

// ---------------- async global -> LDS, 16B per lane ----------------
__device__ __forceinline__ void async_cp16(const void* g, void* l) {
  __builtin_amdgcn_global_load_lds(
      (const __attribute__((address_space(1))) unsigned int*)g,
      (__attribute__((address_space(3))) unsigned int*)l, 16, 0, 0);
}

// ---------------- m97-style GEMM: C[M,N] = A[M,K] * Bt[N,K]^T + bias ----------------
// ACT: 0=none, 1=gelu(tanh), 2=sigmoid.  OUT16: store f16 else f32.
// blockIdx.z offsets: A += z*zA (column offset), Bt += z*zB, bias += z*zBias, C col += z*zC.
#define BM 128
#define BN 128
#define BK 32

template<int ACT, int OUT16>
__global__ __launch_bounds__(256, 2)
void gemm_kernel(const f16* __restrict__ A, long ldA, long zA,
                 const f16* __restrict__ Bt, long zB,
                 const float* __restrict__ bias, long zBias,
                 void* __restrict__ Cv, long ldC, long zC,
                 int K) {
  __shared__ __attribute__((aligned(16))) f16 As[BM * BK];
  __shared__ __attribute__((aligned(16))) f16 Bs[BN * BK];
  const int tid = threadIdx.x;
  const int wave = tid >> 6;
  const int lane = tid & 63;
  const int wm = wave >> 1, wn = wave & 1;
  const long bm = (long)blockIdx.y * BM;
  const long bn = (long)blockIdx.x * BN;
  const int z = blockIdx.z;
  A += (long)z * zA;
  Bt += (long)z * zB;
  bias += (long)z * zBias;
  const long cColOff = (long)z * zC;

  // staging: wave w covers rows [w*32, w*32+32) of each tile; 2 insts of 16 rows.
  const int sRow = wave * 32 + (lane >> 2);
  const int sCol = (lane & 3) * 8;  // halfs
  const f16* gA = A + (bm + sRow) * ldA + sCol;
  const f16* gB = Bt + (bn + sRow) * (long)K + sCol;
  f16* lA = As + wave * 1024;  // wave*2048 bytes
  f16* lB = Bs + wave * 1024;

  f32x4 acc[4][4];
#pragma unroll
  for (int i = 0; i < 4; ++i)
#pragma unroll
    for (int j = 0; j < 4; ++j) {
      acc[i][j][0] = 0.f; acc[i][j][1] = 0.f; acc[i][j][2] = 0.f; acc[i][j][3] = 0.f;
    }

  const int quad = lane >> 4, l16 = lane & 15;

  for (int k0 = 0; k0 < K; k0 += BK) {
    async_cp16(gA, lA);
    async_cp16(gA + 16 * ldA, lA + 512);
    async_cp16(gB, lB);
    async_cp16(gB + 16 * (long)K, lB + 512);
    gA += BK; gB += BK;
    __syncthreads();  // drains vmcnt: LDS tiles ready
    f16x8 af[4], bf[4];
#pragma unroll
    for (int i = 0; i < 4; ++i) {
      af[i] = *(const f16x8*)&As[(wm * 64 + i * 16 + l16) * BK + quad * 8];
      bf[i] = *(const f16x8*)&Bs[(wn * 64 + i * 16 + l16) * BK + quad * 8];
    }
#pragma unroll
    for (int i = 0; i < 4; ++i)
#pragma unroll
      for (int j = 0; j < 4; ++j)
        acc[i][j] = __builtin_amdgcn_mfma_f32_16x16x32_f16(af[i], bf[j], acc[i][j], 0, 0, 0);
    __syncthreads();  // all waves done reading LDS before next overwrite
  }

  // epilogue: C/D layout col=lane&15, row=(lane>>4)*4+reg
#pragma unroll
  for (int i = 0; i < 4; ++i) {
    const long row0 = bm + wm * 64 + i * 16 + quad * 4;
#pragma unroll
    for (int j = 0; j < 4; ++j) {
      const long colIn = bn + wn * 64 + j * 16 + l16;
      const float bv = bias[colIn];
#pragma unroll
      for (int r = 0; r < 4; ++r) {
        float v = acc[i][j][r] + bv;
        if (ACT == 1) {
          float u = v;
          v = 0.5f * u * (1.f + tanhf(0.7978845608028654f * (u + 0.044715f * u * u * u)));
        } else if (ACT == 2) {
          v = 1.f / (1.f + expf(-v));
        }
        const long cidx = (row0 + r) * ldC + cColOff + colIn;
        if (OUT16) ((f16*)Cv)[cidx] = (f16)v;
        else       ((float*)Cv)[cidx] = v;
      }
    }
  }
}

// ---------------- causal depthwise conv (TW=4), f32 in -> f16 out ----------------
__global__ void conv_kernel(const float* __restrict__ xb, const float* __restrict__ cw,
                            const float* __restrict__ cb, f16* __restrict__ out) {
  const int d = blockIdx.x * 256 + threadIdx.x;
  const int t = blockIdx.y;
  const int b = blockIdx.z;
  const long idx = ((long)b * T_DIM + t) * D_DIM + d;
  float acc = cb[d];
#pragma unroll
  for (int i = 0; i < TW_DIM; ++i) {
    const int tt = t - (TW_DIM - 1) + i;
    if (tt >= 0) acc += cw[i * D_DIM + d] * xb[idx + (long)(i - (TW_DIM - 1)) * D_DIM];
  }
  out[idx] = (f16)acc;
}

// ---------------- RG-LRU elementwise: a, norm_x ----------------
__global__ void rglru_ew_kernel(const f16* __restrict__ conv16, const f16* __restrict__ gx16,
                                const f16* __restrict__ ga16, const float* __restrict__ a_param,
                                const int* __restrict__ segpos,
                                f16* __restrict__ a16, f16* __restrict__ nx16) {
  const int d = blockIdx.x * 256 + threadIdx.x;
  const int t = blockIdx.y;
  const int b = blockIdx.z;
  const long idx = ((long)b * T_DIM + t) * D_DIM + d;
  const float ga = (float)ga16[idx];
  const float sp = log1pf(expf(a_param[d]));       // softplus
  const float log_a = -8.f * ga * sp;
  float a = expf(log_a);
  float mult = sqrtf(fmaxf(1.f - expf(2.f * log_a), 0.f));
  if (segpos[b * T_DIM + t] == 0) { a = 0.f; mult = 1.f; }
  const float nx = (float)conv16[idx] * (float)gx16[idx] * mult;
  a16[idx] = (f16)a;
  nx16[idx] = (f16)nx;
}

// ---------------- chunked scan: h_t = a_t h_{t-1} + x_t ----------------
__global__ void scanA_kernel(const f16* __restrict__ a16, const f16* __restrict__ nx16,
                             float* __restrict__ Ac, float* __restrict__ Sc) {
  const int d = blockIdx.x * 256 + threadIdx.x;
  const int c = blockIdx.y;
  const int b = blockIdx.z;
  long base = ((long)b * T_DIM + (long)c * TC) * D_DIM + d;
  float Ap = 1.f, S = 0.f;
  for (int t = 0; t < TC; ++t) {
    const float a = (float)a16[base];
    const float x = (float)nx16[base];
    S = a * S + x;
    Ap *= a;
    base += D_DIM;
  }
  const long cidx = ((long)b * CHUNKS + c) * D_DIM + d;
  Ac[cidx] = Ap;
  Sc[cidx] = S;
}

__global__ void scanB_kernel(const float* __restrict__ Ac, const float* __restrict__ Sc,
                             float* __restrict__ He) {
  const int d = blockIdx.x * 256 + threadIdx.x;
  const int b = blockIdx.z;
  float h = 0.f;
  for (int c = 0; c < CHUNKS; ++c) {
    const long cidx = ((long)b * CHUNKS + c) * D_DIM + d;
    He[cidx] = h;  // h at entry of chunk c
    h = Ac[cidx] * h + Sc[cidx];
  }
}

__global__ void scanC_kernel(const f16* __restrict__ a16, const f16* __restrict__ nx16,
                             const float* __restrict__ He, const f16* __restrict__ y16,
                             f16* __restrict__ hy16) {
  const int d = blockIdx.x * 256 + threadIdx.x;
  const int c = blockIdx.y;
  const int b = blockIdx.z;
  long base = ((long)b * T_DIM + (long)c * TC) * D_DIM + d;
  float h = He[((long)b * CHUNKS + c) * D_DIM + d];
  for (int t = 0; t < TC; ++t) {
    h = (float)a16[base] * h + (float)nx16[base];
    hy16[base] = (f16)(h * (float)y16[base]);
    base += D_DIM;
  }
}

// ---------------- launch ----------------
extern "C" void kernel_launch(void* const* d_in, const int* in_sizes, int n_in,
                              void* d_out, int out_size, void* d_ws, size_t ws_size,
                              hipStream_t stream) {
  const float* x   = (const float*)d_in[0];
  const int*   segp= (const int*)d_in[1];
  const float* Wy  = (const float*)d_in[2];
  const float* by  = (const float*)d_in[3];
  const float* Wx  = (const float*)d_in[4];
  const float* bx  = (const float*)d_in[5];
  const float* cw  = (const float*)d_in[6];
  const float* cb  = (const float*)d_in[7];
  const float* ap  = (const float*)d_in[8];
  const float* igw = (const float*)d_in[9];
  const float* igb = (const float*)d_in[10];
  const float* agw = (const float*)d_in[11];
  const float* agb = (const float*)d_in[12];
  const float* Wo  = (const float*)d_in[13];
  const float* bo  = (const float*)d_in[14];
  float* out = (float*)d_out;
  char* ws = (char*)d_ws;

  const long MD = (long)M_DIM * D_DIM;  // 41,943,040
  // workspace layout (bytes). Liveness-based reuse:
  f16*   x16    = (f16*)(ws + 0);          // dead after GEMMs 1,2 -> reused as a16
  f16*   a16    = (f16*)(ws + 0);
  f16*   y16    = (f16*)(ws + MD * 2);     // live until scanC
  float* xb     = (float*)(ws + MD * 4);   // dead after conv -> gx16/ga16 -> hy16
  f16*   gx16   = (f16*)(ws + MD * 4);
  f16*   ga16   = (f16*)(ws + MD * 6);
  f16*   hy16   = (f16*)(ws + MD * 4);
  f16*   conv16 = (f16*)(ws + MD * 8);
  f16*   nx16   = (f16*)(ws + MD * 10);
  long off = MD * 12;
  f16* Wyt = (f16*)(ws + off); off += (long)D_DIM * D_DIM * 2;
  f16* Wxt = (f16*)(ws + off); off += (long)D_DIM * D_DIM * 2;
  f16* Wot = (f16*)(ws + off); off += (long)D_DIM * D_DIM * 2;
  f16* igt = (f16*)(ws + off); off += (long)H_DIM * DH * DH * 2;
  f16* agt = (f16*)(ws + off); off += (long)H_DIM * DH * DH * 2;
  float* Ac = (float*)(ws + off); off += (long)B_DIM * CHUNKS * D_DIM * 4;
  float* Sc = (float*)(ws + off); off += (long)B_DIM * CHUNKS * D_DIM * 4;
  float* He = (float*)(ws + off); off += (long)B_DIM * CHUNKS * D_DIM * 4;

  dim3 tb(32, 8);
  // 1. x -> f16
  cvt_f16_kernel<<<dim3((unsigned)(MD / 4 / 256)), 256, 0, stream>>>(x, x16, MD / 4);
  // 2. weight transposes -> [N,K] f16
  transpose_cvt_kernel<<<dim3(80, 80, 1), tb, 0, stream>>>(Wy, Wyt, D_DIM, D_DIM);
  transpose_cvt_kernel<<<dim3(80, 80, 1), tb, 0, stream>>>(Wx, Wxt, D_DIM, D_DIM);
  transpose_cvt_kernel<<<dim3(80, 80, 1), tb, 0, stream>>>(Wo, Wot, D_DIM, D_DIM);
  transpose_cvt_kernel<<<dim3(8, 8, 10), tb, 0, stream>>>(igw, igt, DH, DH);
  transpose_cvt_kernel<<<dim3(8, 8, 10), tb, 0, stream>>>(agw, agt, DH, DH);
  // 3. y = gelu(x @ Wy + by) -> f16
  gemm_kernel<1, 1><<<dim3(20, 128, 1), 256, 0, stream>>>(
      x16, D_DIM, 0, Wyt, 0, by, 0, (void*)y16, D_DIM, 0, D_DIM);
  // 4. xb = x @ Wx + bx -> f32
  gemm_kernel<0, 0><<<dim3(20, 128, 1), 256, 0, stream>>>(
      x16, D_DIM, 0, Wxt, 0, bx, 0, (void*)xb, D_DIM, 0, D_DIM);
  // 5. causal conv -> f16
  conv_kernel<<<dim3(10, 4096, 4), 256, 0, stream>>>(xb, cw, cb, conv16);
  // 6/7. block-diagonal gate GEMMs, sigmoid epilogue -> f16
  gemm_kernel<2, 1><<<dim3(2, 128, 10), 256, 0, stream>>>(
      conv16, D_DIM, DH, igt, (long)DH * DH, igb, DH, (void*)gx16, D_DIM, DH, DH);
  gemm_kernel<2, 1><<<dim3(2, 128, 10), 256, 0, stream>>>(
      conv16, D_DIM, DH, agt, (long)DH * DH, agb, DH, (void*)ga16, D_DIM, DH, DH);
  // 8. RG-LRU elementwise: a, norm_x
  rglru_ew_kernel<<<dim3(10, 4096, 4), 256, 0, stream>>>(conv16, gx16, ga16, ap, segp, a16, nx16);
  // 9. chunked scan; phase C fuses h*y -> f16
  scanA_kernel<<<dim3(10, CHUNKS, 4), 256, 0, stream>>>(a16, nx16, Ac, Sc);
  scanB_kernel<<<dim3(10, 1, 4), 256, 0, stream>>>(Ac, Sc, He);
  scanC_kernel<<<dim3(10, CHUNKS, 4), 256, 0, stream>>>(a16, nx16, He, y16, hy16);
  // 10. out = (h*y) @ Wo + bo -> f32
  gemm_kernel<0, 0><<<dim3(20, 128, 1), 256, 0, stream>>>(
      hy16, D_DIM, 0, Wot, 0, bo, 0, (void*)out, D_DIM, 0, D_DIM);
}

// Round 2
// 1613.717 us; speedup vs baseline: 1.1123x; 1.1123x over previous
//
#include <hip/hip_runtime.h>

#define D_DIM 2560
#define T_DIM 4096
#define B_DIM 4
#define H_DIM 10
#define DH 256
#define TW_DIM 4
#define M_DIM (B_DIM * T_DIM)   // 16384
#define CHUNKS 64
#define TC (T_DIM / CHUNKS)     // 64

typedef _Float16 f16;
typedef __attribute__((ext_vector_type(8))) _Float16 f16x8;
typedef __attribute__((ext_vector_type(4))) _Float16 f16x4;
typedef __attribute__((ext_vector_type(2))) _Float16 f16x2;
typedef __attribute__((ext_vector_type(4))) float f32x4;
typedef __attribute__((ext_vector_type(2))) float f32x2;

// ---------------- convert f32 -> f16 (vectorized x4) ----------------
__global__ void cvt_f16_kernel(const float* __restrict__ in, f16* __restrict__ out, long n4) {
  long i = (long)blockIdx.x * blockDim.x + threadIdx.x;
  if (i >= n4) return;
  f32x4 v = ((const f32x4*)in)[i];
  f16x4 o;
  o[0] = (f16)v[0]; o[1] = (f16)v[1]; o[2] = (f16)v[2]; o[3] = (f16)v[3];
  ((f16x4*)out)[i] = o;
}

// ---------------- transpose + convert, 3 separate square sources ----------------
__global__ void transpose_cvt3_kernel(const float* __restrict__ s0, const float* __restrict__ s1,
                                      const float* __restrict__ s2, f16* __restrict__ out,
                                      int R, int C) {
  __shared__ float tile[32][33];
  const int z = blockIdx.z;
  const float* in = (z == 0) ? s0 : ((z == 1) ? s1 : s2);
  out += (long)z * R * C;
  int c0 = blockIdx.x * 32, r0 = blockIdx.y * 32;
  int tx = threadIdx.x, ty = threadIdx.y;
  for (int i = ty; i < 32; i += 8)
    tile[i][tx] = in[(long)(r0 + i) * C + (c0 + tx)];
  __syncthreads();
  for (int i = ty; i < 32; i += 8)
    out[(long)(c0 + i) * R + (r0 + tx)] = (f16)tile[tx][i];
}

// ---------------- transpose + convert, 2 batched sources (ig, ag) ----------------
__global__ void transpose_cvt2_kernel(const float* __restrict__ sa, const float* __restrict__ sb,
                                      f16* __restrict__ out, int R, int C, int half) {
  __shared__ float tile[32][33];
  const int z = blockIdx.z;
  const float* in = (z < half) ? (sa + (long)z * R * C) : (sb + (long)(z - half) * R * C);
  out += (long)z * R * C;
  int c0 = blockIdx.x * 32, r0 = blockIdx.y * 32;
  int tx = threadIdx.x, ty = threadIdx.y;
  for (int i = ty; i < 32; i += 8)
    tile[i][tx] = in[(long)(r0 + i) * C + (c0 + tx)];
  __syncthreads();
  for (int i = ty; i < 32; i += 8)
    out[(long)(c0 + i) * R + (r0 + tx)] = (f16)tile[tx][i];
}

// ---------------- async global -> LDS, 16B per lane ----------------
__device__ __forceinline__ void async_cp16(const void* g, void* l) {
  __builtin_amdgcn_global_load_lds(
      (const __attribute__((address_space(1))) unsigned int*)g,
      (__attribute__((address_space(3))) unsigned int*)l, 16, 0, 0);
}

__device__ __forceinline__ float fast_sigmoid(float v) {
  return 1.f / (1.f + __expf(-v));
}

// ---------------- m97-style GEMM: C[M,N] = A[M,K] * Bt[N,K]^T + bias ----------------
// ACT: 0=none, 1=gelu(tanh approx), 2=sigmoid, 3=sigmoid + fused RG-LRU elementwise.
// OUT16: store f16 else f32.
// blockIdx.z offsets: A += z*zA (col offset), Bt += z*zB, bias += z*zBias, C col += z*zC.
// XOR-swizzled LDS k-chunk layout to kill ds_read_b128 bank conflicts.
#define BM 128
#define BN 128
#define BK 32

template<int ACT, int OUT16>
__global__ __launch_bounds__(256, 2)
void gemm_kernel(const f16* __restrict__ A, long ldA, long zA,
                 const f16* __restrict__ Bt, long zB,
                 const float* __restrict__ bias, long zBias,
                 void* __restrict__ Cv, long ldC, long zC, int K,
                 const f16* __restrict__ cX, const f16* __restrict__ gX,
                 const float* __restrict__ apar, const int* __restrict__ segp,
                 f16* __restrict__ nxOut) {
  __shared__ __attribute__((aligned(16))) f16 As[BM * BK];
  __shared__ __attribute__((aligned(16))) f16 Bs[BN * BK];
  const int tid = threadIdx.x;
  const int wave = tid >> 6;
  const int lane = tid & 63;
  const int wm = wave >> 1, wn = wave & 1;
  const long bm = (long)blockIdx.y * BM;
  const long bn = (long)blockIdx.x * BN;
  const int z = blockIdx.z;
  A += (long)z * zA;
  Bt += (long)z * zB;
  bias += (long)z * zBias;
  const long cColOff = (long)z * zC;

  // staging: wave w covers rows [w*32, w*32+32); 2 insts of 16 rows each.
  // XOR swizzle: lane stages global k-chunk ((lane&3) ^ (row&3)) into its fixed LDS slot.
  const int sRow = wave * 32 + (lane >> 2);
  const int sCol = (((lane & 3) ^ (sRow & 3)) * 8);  // halfs
  const f16* gA = A + (bm + sRow) * ldA + sCol;
  const f16* gB = Bt + (bn + sRow) * (long)K + sCol;
  f16* lA = As + wave * 1024;
  f16* lB = Bs + wave * 1024;

  f32x4 acc[4][4];
#pragma unroll
  for (int i = 0; i < 4; ++i)
#pragma unroll
    for (int j = 0; j < 4; ++j) {
      acc[i][j][0] = 0.f; acc[i][j][1] = 0.f; acc[i][j][2] = 0.f; acc[i][j][3] = 0.f;
    }

  const int quad = lane >> 4, l16 = lane & 15;
  const int rswz = (quad ^ (l16 & 3)) * 8;  // reader compensation: slot = quad ^ (row&3)

  for (int k0 = 0; k0 < K; k0 += BK) {
    async_cp16(gA, lA);
    async_cp16(gA + 16 * ldA, lA + 512);
    async_cp16(gB, lB);
    async_cp16(gB + 16 * (long)K, lB + 512);
    gA += BK; gB += BK;
    __syncthreads();  // drains vmcnt: LDS tiles ready
    f16x8 af[4], bf[4];
#pragma unroll
    for (int i = 0; i < 4; ++i) {
      af[i] = *(const f16x8*)&As[(wm * 64 + i * 16 + l16) * BK + rswz];
      bf[i] = *(const f16x8*)&Bs[(wn * 64 + i * 16 + l16) * BK + rswz];
    }
#pragma unroll
    for (int i = 0; i < 4; ++i)
#pragma unroll
      for (int j = 0; j < 4; ++j)
        acc[i][j] = __builtin_amdgcn_mfma_f32_16x16x32_f16(af[i], bf[j], acc[i][j], 0, 0, 0);
    __syncthreads();
  }

  // epilogue: C/D layout col=lane&15, row=(lane>>4)*4+reg
#pragma unroll
  for (int i = 0; i < 4; ++i) {
    const long row0 = bm + wm * 64 + i * 16 + quad * 4;
#pragma unroll
    for (int j = 0; j < 4; ++j) {
      const long colIn = bn + wn * 64 + j * 16 + l16;
      const long colG = cColOff + colIn;
      const float bv = bias[colIn];
      float sp = 0.f;
      if (ACT == 3) sp = log1pf(__expf(apar[colG]));
#pragma unroll
      for (int r = 0; r < 4; ++r) {
        const long row = row0 + r;
        float v = acc[i][j][r] + bv;
        if (ACT == 1) {
          const float u = v;
          const float t = 0.7978845608028654f * (u + 0.044715f * u * u * u);
          v = u * fast_sigmoid(2.f * t);   // 0.5u(1+tanh t) = u*sigmoid(2t)
        } else if (ACT == 2) {
          v = fast_sigmoid(v);
        }
        const long cidx = row * ldC + colG;
        if (ACT == 3) {
          const float ga = fast_sigmoid(v);
          const float log_a = -8.f * ga * sp;
          float a = __expf(log_a);
          float mult = sqrtf(fmaxf(1.f - __expf(2.f * log_a), 0.f));
          if (segp[row] == 0) { a = 0.f; mult = 1.f; }
          const float nx = (float)cX[cidx] * (float)gX[cidx] * mult;
          ((f16*)Cv)[cidx] = (f16)a;
          nxOut[cidx] = (f16)nx;
        } else if (OUT16) {
          ((f16*)Cv)[cidx] = (f16)v;
        } else {
          ((float*)Cv)[cidx] = v;
        }
      }
    }
  }
}

// ---------------- causal depthwise conv (TW=4), f16 in -> f16 out, x4 ----------------
__global__ void conv_kernel(const f16* __restrict__ xb, const float* __restrict__ cw,
                            const float* __restrict__ cb, f16* __restrict__ out) {
  const int d4 = blockIdx.x * 128 + threadIdx.x;  // over D/4 = 640
  const int t = blockIdx.y;
  const int b = blockIdx.z;
  const long idx4 = ((long)b * T_DIM + t) * (D_DIM / 4) + d4;
  f32x4 acc = ((const f32x4*)cb)[d4];
#pragma unroll
  for (int i = 0; i < TW_DIM; ++i) {
    const int tt = t - (TW_DIM - 1) + i;
    if (tt >= 0) {
      f16x4 xv = ((const f16x4*)xb)[idx4 + (long)(i - (TW_DIM - 1)) * (D_DIM / 4)];
      f32x4 w = ((const f32x4*)cw)[i * (D_DIM / 4) + d4];
      acc[0] += w[0] * (float)xv[0];
      acc[1] += w[1] * (float)xv[1];
      acc[2] += w[2] * (float)xv[2];
      acc[3] += w[3] * (float)xv[3];
    }
  }
  f16x4 o;
  o[0] = (f16)acc[0]; o[1] = (f16)acc[1]; o[2] = (f16)acc[2]; o[3] = (f16)acc[3];
  ((f16x4*)out)[idx4] = o;
}

// ---------------- chunked scan: h_t = a_t h_{t-1} + x_t (x2 vectorized) ----------------
__global__ void scanA_kernel(const f16* __restrict__ a16, const f16* __restrict__ nx16,
                             float* __restrict__ Ac, float* __restrict__ Sc) {
  const int d2 = blockIdx.x * 256 + threadIdx.x;  // over D/2 = 1280
  const int c = blockIdx.y;
  const int b = blockIdx.z;
  long base2 = ((long)b * T_DIM + (long)c * TC) * (D_DIM / 2) + d2;
  float Ap0 = 1.f, Ap1 = 1.f, S0 = 0.f, S1 = 0.f;
  for (int t = 0; t < TC; ++t) {
    f16x2 av = ((const f16x2*)a16)[base2];
    f16x2 xv = ((const f16x2*)nx16)[base2];
    S0 = (float)av[0] * S0 + (float)xv[0];
    S1 = (float)av[1] * S1 + (float)xv[1];
    Ap0 *= (float)av[0];
    Ap1 *= (float)av[1];
    base2 += D_DIM / 2;
  }
  const long cidx2 = ((long)b * CHUNKS + c) * (D_DIM / 2) + d2;
  f32x2 av_; av_[0] = Ap0; av_[1] = Ap1;
  f32x2 sv_; sv_[0] = S0; sv_[1] = S1;
  ((f32x2*)Ac)[cidx2] = av_;
  ((f32x2*)Sc)[cidx2] = sv_;
}

__global__ void scanB_kernel(const float* __restrict__ Ac, const float* __restrict__ Sc,
                             float* __restrict__ He) {
  const int d = blockIdx.x * 256 + threadIdx.x;
  const int b = blockIdx.z;
  float h = 0.f;
  for (int c = 0; c < CHUNKS; ++c) {
    const long cidx = ((long)b * CHUNKS + c) * D_DIM + d;
    He[cidx] = h;  // h at entry of chunk c
    h = Ac[cidx] * h + Sc[cidx];
  }
}

__global__ void scanC_kernel(const f16* __restrict__ a16, const f16* __restrict__ nx16,
                             const float* __restrict__ He, const f16* __restrict__ y16,
                             f16* __restrict__ hy16) {
  const int d2 = blockIdx.x * 256 + threadIdx.x;
  const int c = blockIdx.y;
  const int b = blockIdx.z;
  long base2 = ((long)b * T_DIM + (long)c * TC) * (D_DIM / 2) + d2;
  f32x2 hv = ((const f32x2*)He)[((long)b * CHUNKS + c) * (D_DIM / 2) + d2];
  float h0 = hv[0], h1 = hv[1];
  for (int t = 0; t < TC; ++t) {
    f16x2 av = ((const f16x2*)a16)[base2];
    f16x2 xv = ((const f16x2*)nx16)[base2];
    f16x2 yv = ((const f16x2*)y16)[base2];
    h0 = (float)av[0] * h0 + (float)xv[0];
    h1 = (float)av[1] * h1 + (float)xv[1];
    f16x2 o;
    o[0] = (f16)(h0 * (float)yv[0]);
    o[1] = (f16)(h1 * (float)yv[1]);
    ((f16x2*)hy16)[base2] = o;
    base2 += D_DIM / 2;
  }
}

// ---------------- launch ----------------
extern "C" void kernel_launch(void* const* d_in, const int* in_sizes, int n_in,
                              void* d_out, int out_size, void* d_ws, size_t ws_size,
                              hipStream_t stream) {
  const float* x   = (const float*)d_in[0];
  const int*   segp= (const int*)d_in[1];
  const float* Wy  = (const float*)d_in[2];
  const float* by  = (const float*)d_in[3];
  const float* Wx  = (const float*)d_in[4];
  const float* bx  = (const float*)d_in[5];
  const float* cw  = (const float*)d_in[6];
  const float* cb  = (const float*)d_in[7];
  const float* ap  = (const float*)d_in[8];
  const float* igw = (const float*)d_in[9];
  const float* igb = (const float*)d_in[10];
  const float* agw = (const float*)d_in[11];
  const float* agb = (const float*)d_in[12];
  const float* Wo  = (const float*)d_in[13];
  const float* bo  = (const float*)d_in[14];
  float* out = (float*)d_out;
  char* ws = (char*)d_ws;

  const long MD = (long)M_DIM * D_DIM;  // 41,943,040
  // workspace layout (liveness-based reuse):
  f16*   x16    = (f16*)(ws + 0);          // dead after GEMMs 1,2 -> a16
  f16*   a16    = (f16*)(ws + 0);
  f16*   y16    = (f16*)(ws + MD * 2);     // live until scanC
  f16*   xb2    = (f16*)(ws + MD * 4);     // dead after conv -> gx16 -> hy16
  f16*   gx16   = (f16*)(ws + MD * 4);
  f16*   hy16   = (f16*)(ws + MD * 4);
  f16*   conv16 = (f16*)(ws + MD * 6);     // live until ag-gate epilogue
  f16*   nx16   = (f16*)(ws + MD * 8);
  long off = MD * 10;
  f16* Wt  = (f16*)(ws + off); off += 3L * D_DIM * D_DIM * 2;   // Wyt,Wxt,Wot contiguous
  f16* igagt = (f16*)(ws + off); off += 20L * DH * DH * 2;      // igt(10) then agt(10)
  float* Ac = (float*)(ws + off); off += (long)B_DIM * CHUNKS * D_DIM * 4;
  float* Sc = (float*)(ws + off); off += (long)B_DIM * CHUNKS * D_DIM * 4;
  float* He = (float*)(ws + off); off += (long)B_DIM * CHUNKS * D_DIM * 4;
  f16* Wyt = Wt;
  f16* Wxt = Wt + (long)D_DIM * D_DIM;
  f16* Wot = Wt + 2L * D_DIM * D_DIM;
  f16* igt = igagt;
  f16* agt = igagt + 10L * DH * DH;

  dim3 tb(32, 8);
  // 1. x -> f16
  cvt_f16_kernel<<<dim3((unsigned)(MD / 4 / 256)), 256, 0, stream>>>(x, x16, MD / 4);
  // 2. weight transposes -> [N,K] f16
  transpose_cvt3_kernel<<<dim3(80, 80, 3), tb, 0, stream>>>(Wy, Wx, Wo, Wt, D_DIM, D_DIM);
  transpose_cvt2_kernel<<<dim3(8, 8, 20), tb, 0, stream>>>(igw, agw, igagt, DH, DH, 10);
  // 3. y = gelu(x @ Wy + by) -> f16
  gemm_kernel<1, 1><<<dim3(20, 128, 1), 256, 0, stream>>>(
      x16, D_DIM, 0, Wyt, 0, by, 0, (void*)y16, D_DIM, 0, D_DIM,
      nullptr, nullptr, nullptr, nullptr, nullptr);
  // 4. xb = x @ Wx + bx -> f16
  gemm_kernel<0, 1><<<dim3(20, 128, 1), 256, 0, stream>>>(
      x16, D_DIM, 0, Wxt, 0, bx, 0, (void*)xb2, D_DIM, 0, D_DIM,
      nullptr, nullptr, nullptr, nullptr, nullptr);
  // 5. causal conv -> f16
  conv_kernel<<<dim3(5, 4096, 4), 128, 0, stream>>>(xb2, cw, cb, conv16);
  // 6. gate_x = sigmoid(blockdiag(conv)) -> f16
  gemm_kernel<2, 1><<<dim3(2, 128, 10), 256, 0, stream>>>(
      conv16, D_DIM, DH, igt, (long)DH * DH, igb, DH, (void*)gx16, D_DIM, DH, DH,
      nullptr, nullptr, nullptr, nullptr, nullptr);
  // 7. gate_a GEMM + fused RG-LRU elementwise -> a16, nx16
  gemm_kernel<3, 1><<<dim3(2, 128, 10), 256, 0, stream>>>(
      conv16, D_DIM, DH, agt, (long)DH * DH, agb, DH, (void*)a16, D_DIM, DH, DH,
      conv16, gx16, ap, segp, nx16);
  // 8. chunked scan; phase C fuses h*y -> f16
  scanA_kernel<<<dim3(5, CHUNKS, 4), 256, 0, stream>>>(a16, nx16, Ac, Sc);
  scanB_kernel<<<dim3(10, 1, 4), 256, 0, stream>>>(Ac, Sc, He);
  scanC_kernel<<<dim3(5, CHUNKS, 4), 256, 0, stream>>>(a16, nx16, He, y16, hy16);
  // 9. out = (h*y) @ Wo + bo -> f32
  gemm_kernel<0, 0><<<dim3(20, 128, 1), 256, 0, stream>>>(
      hy16, D_DIM, 0, Wot, 0, bo, 0, (void*)out, D_DIM, 0, D_DIM,
      nullptr, nullptr, nullptr, nullptr, nullptr);
}